// Round 1
// baseline (1116.091 us; speedup 1.0000x reference)
//
#include <hip/hip_runtime.h>

#define GRID_NN 128
#define NV (GRID_NN * GRID_NN)   // 16384
#define BATCH 8
#define NDIM 3

__global__ void zero_out_kernel(float* out) {
    if (threadIdx.x < BATCH) out[threadIdx.x] = 0.0f;
}

// One thread per (vertex, batch). Exploits the banded 7-nonzero structure of the
// grid-triangulated Laplacian: nonzeros of row i only at columns i + {-128,-127,-1,0,1,127,128}.
// Values are READ from the dense L (robust to normalization details); structural
// zeros at boundaries contribute nothing.
__global__ __launch_bounds__(256) void lap_loss_kernel(const float* __restrict__ L,
                                                       const float* __restrict__ x,
                                                       float* __restrict__ out) {
    const int i = blockIdx.x * blockDim.x + threadIdx.x;  // vertex id, exact cover of NV
    const int b = blockIdx.y;                              // batch

    const int offs[7] = {-GRID_NN, -GRID_NN + 1, -1, 0, 1, GRID_NN - 1, GRID_NN};

    float w[7];
    int   jn[7];
    const long rowbase = (long)i * NV;
#pragma unroll
    for (int k = 0; k < 7; ++k) {
        int j = i + offs[k];
        bool valid = (j >= 0) && (j < NV);
        jn[k] = valid ? j : i;                 // safe index; weight forced to 0 below
        w[k]  = valid ? L[rowbase + j] : 0.0f;
    }

    const float* __restrict__ xb = x + (size_t)b * (NV * NDIM);
    float y0 = 0.0f, y1 = 0.0f, y2 = 0.0f;
#pragma unroll
    for (int k = 0; k < 7; ++k) {
        const float* xj = xb + jn[k] * NDIM;
        float wk = w[k];
        y0 += wk * xj[0];
        y1 += wk * xj[1];
        y2 += wk * xj[2];
    }
    float acc = y0 * y0 + y1 * y1 + y2 * y2;

    // wave-64 shuffle reduction
#pragma unroll
    for (int s = 32; s > 0; s >>= 1) acc += __shfl_down(acc, s, 64);

    __shared__ float lds[4];
    const int lane = threadIdx.x & 63;
    const int wid  = threadIdx.x >> 6;
    if (lane == 0) lds[wid] = acc;
    __syncthreads();
    if (threadIdx.x == 0) {
        float s = lds[0] + lds[1] + lds[2] + lds[3];
        atomicAdd(&out[b], s * (1.0f / (float)(NV * NDIM)));
    }
}

extern "C" void kernel_launch(void* const* d_in, const int* in_sizes, int n_in,
                              void* d_out, int out_size, void* d_ws, size_t ws_size,
                              hipStream_t stream) {
    const float* L = (const float*)d_in[0];   // [NV, NV] fp32
    const float* x = (const float*)d_in[1];   // [BATCH, NV, 3] fp32
    float* out = (float*)d_out;               // [BATCH] fp32

    zero_out_kernel<<<1, 64, 0, stream>>>(out);

    dim3 grid(NV / 256, BATCH);
    lap_loss_kernel<<<grid, 256, 0, stream>>>(L, x, out);
}